// Round 4
// baseline (229.761 us; speedup 1.0000x reference)
//
#include <hip/hip_runtime.h>

// dense_image_warp: B=8, H=1024, W=768, C=3, fp32.
// R4: cut VMEM instruction count (bottleneck = per-instruction divergent
// address processing, ~43 cyc/VMEM-instr measured in R3, HBM nearly idle).
//  - gathers: per row, 6 contiguous floats at 3*x0 -> dwordx4 + dwordx2
//    (12 scalar loads -> 4 vector loads)
//  - stores: stage 3072 B block output in LDS, 192 lanes do coalesced
//    16 B nontemporal stores (12 wave-store-instrs/block -> 3)
//  - keep R3's XCD swizzle (FETCH 307->61 MB) + nt flow load.

constexpr int B = 8;
constexpr int H = 1024;
constexpr int W = 768;   // 3 blocks of 256 per row
constexpr int C = 3;
constexpr int XBLKS = W / 256;            // 3
constexpr int BLOCKS_PER_XCD = (B * H * XBLKS) / 8;  // 3072

typedef float vfloat2 __attribute__((ext_vector_type(2)));
typedef float vfloat4 __attribute__((ext_vector_type(4)));
typedef float vfloat2_a4 __attribute__((ext_vector_type(2), aligned(4)));
typedef float vfloat4_a4 __attribute__((ext_vector_type(4), aligned(4)));

__global__ __launch_bounds__(256) void warp_kernel(
    const float* __restrict__ image,   // [B,H,W,3]
    const float* __restrict__ flow,    // [B,H,W,2]
    float* __restrict__ out)           // [B,H,W,3]
{
    __shared__ float sbuf[W];          // 768 floats = 3072 B = block's output

    // ---- XCD-aware decomposition (R3) ----
    const int flat = blockIdx.x;           // 0..24575
    const int xcd  = flat & 7;
    const int seq  = flat >> 3;
    const int band = xcd * BLOCKS_PER_XCD + seq;
    const int xblk    = band % XBLKS;
    const int rowflat = band / XBLKS;      // 0..8191
    const int y = rowflat & (H - 1);
    const int b = rowflat >> 10;

    const int tid = threadIdx.x;
    const int x = xblk * 256 + tid;
    const size_t pix = ((size_t)b * H + y) * W + x;

    // flow: coalesced 8B, read-once -> non-temporal
    const vfloat2 f = __builtin_nontemporal_load((const vfloat2*)flow + pix);
    const float qy = (float)y - f.x;
    const float qx = (float)x - f.y;

    float y0f = floorf(qy);
    float x0f = floorf(qx);
    y0f = fminf(fmaxf(y0f, 0.0f), (float)(H - 2));
    x0f = fminf(fmaxf(x0f, 0.0f), (float)(W - 2));
    const float ay = fminf(fmaxf(qy - y0f, 0.0f), 1.0f);
    const float ax = fminf(fmaxf(qx - x0f, 0.0f), 1.0f);

    const int y0 = (int)y0f;
    const int x0 = (int)x0f;

    // 6 contiguous floats per row: [tl.r tl.g tl.b tr.r tr.g tr.b]
    const float* __restrict__ top = image + (((size_t)b * H + y0) * W + x0) * C;
    const float* __restrict__ bot = top + (size_t)W * C;

    const vfloat4 t4 = *(const vfloat4_a4*)top;        // tl.rgb, tr.r
    const vfloat2 t2 = *(const vfloat2_a4*)(top + 4);  // tr.g, tr.b
    const vfloat4 b4 = *(const vfloat4_a4*)bot;
    const vfloat2 b2 = *(const vfloat2_a4*)(bot + 4);

    const float tl0 = t4.x, tl1 = t4.y, tl2 = t4.z;
    const float tr0 = t4.w, tr1 = t2.x, tr2 = t2.y;
    const float bl0 = b4.x, bl1 = b4.y, bl2 = b4.z;
    const float br0 = b4.w, br1 = b2.x, br2 = b2.y;

    const float tp0 = tl0 + ax * (tr0 - tl0);
    const float tp1 = tl1 + ax * (tr1 - tl1);
    const float tp2 = tl2 + ax * (tr2 - tl2);
    const float bo0 = bl0 + ax * (br0 - bl0);
    const float bo1 = bl1 + ax * (br1 - bl1);
    const float bo2 = bl2 + ax * (br2 - bl2);

    // stage result in LDS (stride-12 writes: bank = 3i mod 32, conflict-free)
    sbuf[tid * 3 + 0] = tp0 + ay * (bo0 - tp0);
    sbuf[tid * 3 + 1] = tp1 + ay * (bo1 - tp1);
    sbuf[tid * 3 + 2] = tp2 + ay * (bo2 - tp2);
    __syncthreads();

    // coalesced 16B nontemporal stores: 192 lanes cover 3072 B
    if (tid < (W * C / XBLKS) / 4) {   // 192
        const vfloat4 v = ((const vfloat4*)sbuf)[tid];
        float* const obase = out + (((size_t)b * H + y) * W + (size_t)xblk * 256) * C;
        __builtin_nontemporal_store(v, (vfloat4*)obase + tid);
    }
}

extern "C" void kernel_launch(void* const* d_in, const int* in_sizes, int n_in,
                              void* d_out, int out_size, void* d_ws, size_t ws_size,
                              hipStream_t stream) {
    const float* image = (const float*)d_in[0];
    const float* flow  = (const float*)d_in[1];
    float* out = (float*)d_out;

    dim3 grid(B * H * XBLKS);   // 24576 blocks, flat
    dim3 block(256);
    warp_kernel<<<grid, block, 0, stream>>>(image, flow, out);
}

// Round 5
// 228.094 us; speedup vs baseline: 1.0073x; 1.0073x over previous
//
#include <hip/hip_runtime.h>

// dense_image_warp: B=8, H=1024, W=768, C=3, fp32.
// R5: serve gathers from LDS instead of L1 (R1/R3/R4 all pinned at ~110us
// regardless of VMEM instr count and HBM bytes -> bottleneck is the L1
// miss/fill path on row-divergent gathers; window per block 123KB >> 32KB L1).
// Each block: 32x32 output tile; stage 65-row x 64-px x 3ch image window
// (49.9 KB) into LDS via coalesced float4; bilinear from LDS; global
// fallback for the ~0.4% of pixels whose flow exceeds the halo (+-16 y,
// +-15 x). LDS stride 192 floats == 0 mod 32 banks: y-divergence costs no
// bank conflicts; 3*x pattern is near-bijective mod 32.

constexpr int B = 8;
constexpr int H = 1024;
constexpr int W = 768;
constexpr int C = 3;

constexpr int TY = 32, TX = 32;          // output tile
constexpr int WIN_ROWS = 65;             // TY + 2*16 + 1
constexpr int WIN_COLS = 64;             // TX + 2*15 + 2
constexpr int WSTRIDE = WIN_COLS * C;    // 192 floats (=768 B, 16B-aligned rows)
constexpr int TILES_X = W / TX;          // 24
constexpr int TILES_Y = H / TY;          // 32
constexpr int TILES_PER_B = TILES_X * TILES_Y;  // 768 ( == blocks per XCD )

typedef float vfloat2 __attribute__((ext_vector_type(2)));
typedef float vfloat4 __attribute__((ext_vector_type(4)));
typedef float vfloat2_a4 __attribute__((ext_vector_type(2), aligned(4)));
typedef float vfloat4_a4 __attribute__((ext_vector_type(4), aligned(4)));

__global__ __launch_bounds__(256) void warp_kernel(
    const float* __restrict__ image,   // [B,H,W,3]
    const float* __restrict__ flow,    // [B,H,W,2]
    float* __restrict__ out)           // [B,H,W,3]
{
    __shared__ float win[WIN_ROWS * WSTRIDE];   // 12480 floats = 49920 B

    // ---- XCD-aware decomposition: blockIdx%8 = XCD, each XCD owns batch b.
    // 6144 blocks total; 768 tiles per batch == blocks per XCD.
    const int flat = blockIdx.x;            // 0..6143
    const int b    = flat & 7;              // xcd == batch
    const int s    = flat >> 3;             // 0..767, temporal order in XCD
    const int ty   = s / TILES_X;
    const int tx   = s - ty * TILES_X;
    const int Y0 = ty * TY, X0 = tx * TX;

    const int rowLo = min(max(Y0 - 16, 0), H - WIN_ROWS);   // 0..959
    const int colLo = min(max(X0 - 15, 0), W - WIN_COLS);   // 0..704

    // ---- stage window: 65 rows x 48 float4, fully coalesced ----
    const float* gwin = image + ((size_t)b * H + rowLo) * (W * C) + colLo * C;
    for (int i = threadIdx.x; i < WIN_ROWS * (WSTRIDE / 4); i += 256) {
        const int r = i / (WSTRIDE / 4);          // /48 -> magic mul
        const int c = i - r * (WSTRIDE / 4);
        const vfloat4 v = *(const vfloat4_a4*)(gwin + (size_t)r * (W * C) + c * 4);
        *(vfloat4*)&win[r * WSTRIDE + c * 4] = v; // 16B-aligned LDS write
    }
    __syncthreads();

    // ---- compute: 4 px per thread ----
#pragma unroll
    for (int k = 0; k < 4; ++k) {
        const int p   = threadIdx.x + k * 256;    // 0..1023
        const int py  = p >> 5;                   // 0..31
        const int pxx = p & 31;
        const int y = Y0 + py;
        const int x = X0 + pxx;
        const size_t pix = ((size_t)b * H + y) * W + x;

        const vfloat2 f = __builtin_nontemporal_load((const vfloat2*)flow + pix);
        const float qy = (float)y - f.x;
        const float qx = (float)x - f.y;

        float y0f = floorf(qy);
        float x0f = floorf(qx);
        y0f = fminf(fmaxf(y0f, 0.0f), (float)(H - 2));
        x0f = fminf(fmaxf(x0f, 0.0f), (float)(W - 2));
        const float ay = fminf(fmaxf(qy - y0f, 0.0f), 1.0f);
        const float ax = fminf(fmaxf(qx - x0f, 0.0f), 1.0f);

        const int y0 = (int)y0f;
        const int x0 = (int)x0f;

        float tl0, tl1, tl2, tr0, tr1, tr2, bl0, bl1, bl2, br0, br1, br2;

        const bool inwin = (y0 >= rowLo) & (y0 <= rowLo + WIN_ROWS - 2) &
                           (x0 >= colLo) & (x0 <= colLo + WIN_COLS - 2);
        if (inwin) {
            const float* t = &win[(y0 - rowLo) * WSTRIDE + (x0 - colLo) * C];
            tl0 = t[0]; tl1 = t[1]; tl2 = t[2];
            tr0 = t[3]; tr1 = t[4]; tr2 = t[5];
            const float* bo = t + WSTRIDE;
            bl0 = bo[0]; bl1 = bo[1]; bl2 = bo[2];
            br0 = bo[3]; br1 = bo[4]; br2 = bo[5];
        } else {
            // rare (~0.4% of px): flow beyond halo -> direct global bilinear
            const float* top = image + (((size_t)b * H + y0) * W + x0) * C;
            const float* bot = top + (size_t)W * C;
            const vfloat4 t4 = *(const vfloat4_a4*)top;
            const vfloat2 t2 = *(const vfloat2_a4*)(top + 4);
            const vfloat4 b4 = *(const vfloat4_a4*)bot;
            const vfloat2 b2 = *(const vfloat2_a4*)(bot + 4);
            tl0 = t4.x; tl1 = t4.y; tl2 = t4.z;
            tr0 = t4.w; tr1 = t2.x; tr2 = t2.y;
            bl0 = b4.x; bl1 = b4.y; bl2 = b4.z;
            br0 = b4.w; br1 = b2.x; br2 = b2.y;
        }

        const float tp0 = tl0 + ax * (tr0 - tl0);
        const float tp1 = tl1 + ax * (tr1 - tl1);
        const float tp2 = tl2 + ax * (tr2 - tl2);
        const float bo0 = bl0 + ax * (br0 - bl0);
        const float bo1 = bl1 + ax * (br1 - bl1);
        const float bo2 = bl2 + ax * (br2 - bl2);

        float* o = out + pix * C;
        __builtin_nontemporal_store(tp0 + ay * (bo0 - tp0), &o[0]);
        __builtin_nontemporal_store(tp1 + ay * (bo1 - tp1), &o[1]);
        __builtin_nontemporal_store(tp2 + ay * (bo2 - tp2), &o[2]);
    }
}

extern "C" void kernel_launch(void* const* d_in, const int* in_sizes, int n_in,
                              void* d_out, int out_size, void* d_ws, size_t ws_size,
                              hipStream_t stream) {
    const float* image = (const float*)d_in[0];
    const float* flow  = (const float*)d_in[1];
    float* out = (float*)d_out;

    dim3 grid(B * TILES_PER_B);   // 6144 blocks
    dim3 block(256);
    warp_kernel<<<grid, block, 0, stream>>>(image, flow, out);
}

// Round 6
// 178.731 us; speedup vs baseline: 1.2855x; 1.2762x over previous
//
#include <hip/hip_runtime.h>

// dense_image_warp: B=8, H=1024, W=768, C=3, fp32.
// R6 = R5 (LDS-served gathers, XCD swizzle) + ASYNC staging:
//   __builtin_amdgcn_global_load_lds width=16 issues all ~12 staging
//   wave-instrs with no intervening s_waitcnt (R5's loop serialized
//   12 x ~900cyc HBM latency per wave -> ~100k cycles/CU total).
//   Flow loads issued before the barrier to hide under staging latency.
// LDS dest constraint: wave-uniform base + lane*16 -> each issue fills 64
// consecutive float4 slots; per-lane global addr = window (r,c) decomposed.
// colLo aligned to 4 px so all 16B global loads are 16B-aligned.

constexpr int B = 8;
constexpr int H = 1024;
constexpr int W = 768;
constexpr int C = 3;

constexpr int TY = 32, TX = 32;          // output tile
constexpr int WIN_ROWS = 65;             // TY + 16 up + 16 down + 1
constexpr int WIN_COLS = 64;             // TX + ~15 left + ~15 right + 2
constexpr int WSTRIDE = WIN_COLS * C;    // 192 floats = 768 B per window row
constexpr int CHUNKS  = WIN_ROWS * (WSTRIDE / 4);   // 3120 float4 chunks
constexpr int TILES_X = W / TX;          // 24
constexpr int TILES_Y = H / TY;          // 32
constexpr int TILES_PER_B = TILES_X * TILES_Y;  // 768

typedef float vfloat2 __attribute__((ext_vector_type(2)));
typedef float vfloat4 __attribute__((ext_vector_type(4)));
typedef float vfloat2_a4 __attribute__((ext_vector_type(2), aligned(4)));
typedef float vfloat4_a4 __attribute__((ext_vector_type(4), aligned(4)));

__global__ __launch_bounds__(256) void warp_kernel(
    const float* __restrict__ image,   // [B,H,W,3]
    const float* __restrict__ flow,    // [B,H,W,2]
    float* __restrict__ out)           // [B,H,W,3]
{
    // +64 floats padding: clamped tail lanes of the last staging issue land here
    __shared__ float win[WIN_ROWS * WSTRIDE + 64];   // 50176 B

    // ---- XCD-aware decomposition: blockIdx%8 = XCD = batch ----
    const int flat = blockIdx.x;            // 0..6143
    const int b    = flat & 7;
    const int s    = flat >> 3;             // 0..767 temporal order in XCD
    const int ty   = s / TILES_X;
    const int tx   = s - ty * TILES_X;
    const int Y0 = ty * TY, X0 = tx * TX;

    const int rowLo = min(max(Y0 - 16, 0), H - WIN_ROWS);          // any
    const int colLo = min(max((X0 - 15) & ~3, 0), W - WIN_COLS);   // mult of 4

    const int lane = threadIdx.x & 63;
    const int wv   = threadIdx.x >> 6;      // 0..3

    // ---- async staging: issue all global_load_lds, no waits ----
    // issue j covers float4 chunks [j*64, j*64+63]; j = wv, wv+4, ...
    const float* gwin = image + ((size_t)b * H + rowLo) * (W * C) + colLo * C;
#pragma unroll 1
    for (int j = wv; j * 64 < CHUNKS; j += 4) {
        int ci = j * 64 + lane;
        if (ci >= CHUNKS) ci = CHUNKS - 1;        // tail clamp -> LDS padding
        const int r = ci / 48;                    // magic-mul div
        const int c = ci - r * 48;
        const float* g = gwin + (size_t)r * (W * C) + c * 4;
        __builtin_amdgcn_global_load_lds(
            (const __attribute__((address_space(1))) void*)g,
            (__attribute__((address_space(3))) void*)(win + (size_t)j * 256),
            16, 0, 0);
    }

    // ---- flow loads issued before barrier: latency hides under staging ----
    vfloat2 f[4];
#pragma unroll
    for (int k = 0; k < 4; ++k) {
        const int p   = threadIdx.x + k * 256;
        const int py  = p >> 5;
        const int pxx = p & 31;
        const size_t pix = ((size_t)b * H + (Y0 + py)) * W + (X0 + pxx);
        f[k] = __builtin_nontemporal_load((const vfloat2*)flow + pix);
    }

    __syncthreads();   // drains vmcnt: staging + flow complete

    // ---- compute: 4 px per thread, gathers served from LDS ----
#pragma unroll
    for (int k = 0; k < 4; ++k) {
        const int p   = threadIdx.x + k * 256;
        const int py  = p >> 5;
        const int pxx = p & 31;
        const int y = Y0 + py;
        const int x = X0 + pxx;
        const size_t pix = ((size_t)b * H + y) * W + x;

        const float qy = (float)y - f[k].x;
        const float qx = (float)x - f[k].y;

        float y0f = floorf(qy);
        float x0f = floorf(qx);
        y0f = fminf(fmaxf(y0f, 0.0f), (float)(H - 2));
        x0f = fminf(fmaxf(x0f, 0.0f), (float)(W - 2));
        const float ay = fminf(fmaxf(qy - y0f, 0.0f), 1.0f);
        const float ax = fminf(fmaxf(qx - x0f, 0.0f), 1.0f);

        const int y0 = (int)y0f;
        const int x0 = (int)x0f;

        float tl0, tl1, tl2, tr0, tr1, tr2, bl0, bl1, bl2, br0, br1, br2;

        const bool inwin = (y0 >= rowLo) & (y0 <= rowLo + WIN_ROWS - 2) &
                           (x0 >= colLo) & (x0 <= colLo + WIN_COLS - 2);
        if (inwin) {
            const float* t = &win[(y0 - rowLo) * WSTRIDE + (x0 - colLo) * C];
            tl0 = t[0]; tl1 = t[1]; tl2 = t[2];
            tr0 = t[3]; tr1 = t[4]; tr2 = t[5];
            const float* bo = t + WSTRIDE;
            bl0 = bo[0]; bl1 = bo[1]; bl2 = bo[2];
            br0 = bo[3]; br1 = bo[4]; br2 = bo[5];
        } else {
            // rare: flow beyond halo -> direct global bilinear
            const float* top = image + (((size_t)b * H + y0) * W + x0) * C;
            const float* bot = top + (size_t)W * C;
            const vfloat4 t4 = *(const vfloat4_a4*)top;
            const vfloat2 t2 = *(const vfloat2_a4*)(top + 4);
            const vfloat4 b4 = *(const vfloat4_a4*)bot;
            const vfloat2 b2 = *(const vfloat2_a4*)(bot + 4);
            tl0 = t4.x; tl1 = t4.y; tl2 = t4.z;
            tr0 = t4.w; tr1 = t2.x; tr2 = t2.y;
            bl0 = b4.x; bl1 = b4.y; bl2 = b4.z;
            br0 = b4.w; br1 = b2.x; br2 = b2.y;
        }

        const float tp0 = tl0 + ax * (tr0 - tl0);
        const float tp1 = tl1 + ax * (tr1 - tl1);
        const float tp2 = tl2 + ax * (tr2 - tl2);
        const float bo0 = bl0 + ax * (br0 - bl0);
        const float bo1 = bl1 + ax * (br1 - bl1);
        const float bo2 = bl2 + ax * (br2 - bl2);

        float* o = out + pix * C;
        __builtin_nontemporal_store(tp0 + ay * (bo0 - tp0), &o[0]);
        __builtin_nontemporal_store(tp1 + ay * (bo1 - tp1), &o[1]);
        __builtin_nontemporal_store(tp2 + ay * (bo2 - tp2), &o[2]);
    }
}

extern "C" void kernel_launch(void* const* d_in, const int* in_sizes, int n_in,
                              void* d_out, int out_size, void* d_ws, size_t ws_size,
                              hipStream_t stream) {
    const float* image = (const float*)d_in[0];
    const float* flow  = (const float*)d_in[1];
    float* out = (float*)d_out;

    dim3 grid(B * TILES_PER_B);   // 6144 blocks
    dim3 block(256);
    warp_kernel<<<grid, block, 0, stream>>>(image, flow, out);
}

// Round 7
// 176.559 us; speedup vs baseline: 1.3013x; 1.0123x over previous
//
#include <hip/hip_runtime.h>

// dense_image_warp: B=8, H=1024, W=768, C=3, fp32.
// R7 = R6 (async global_load_lds staging, LDS gathers, XCD swizzle) with
// 512-thread blocks / 2 px per thread. Same 32x32 tile, same 50 KB window,
// so LDS still allows 3 blocks/CU — but now 24 waves/CU instead of 12
// (R6: all pipes <35% busy, occupancy 28% -> limiter is in-flight
// parallelism across the barrier-separated stage/compute phases).

constexpr int B = 8;
constexpr int H = 1024;
constexpr int W = 768;
constexpr int C = 3;

constexpr int TY = 32, TX = 32;          // output tile
constexpr int WIN_ROWS = 65;             // TY + 16 up + 16 down + 1
constexpr int WIN_COLS = 64;             // TX + ~15 halo each side + 2
constexpr int WSTRIDE = WIN_COLS * C;    // 192 floats = 768 B per window row
constexpr int CHUNKS  = WIN_ROWS * (WSTRIDE / 4);   // 3120 float4 chunks
constexpr int TILES_X = W / TX;          // 24
constexpr int TILES_Y = H / TY;          // 32
constexpr int TILES_PER_B = TILES_X * TILES_Y;  // 768

constexpr int NTHREADS = 512;            // 8 waves/block
constexpr int PX_PER_T = (TY * TX) / NTHREADS;  // 2

typedef float vfloat2 __attribute__((ext_vector_type(2)));
typedef float vfloat4 __attribute__((ext_vector_type(4)));
typedef float vfloat2_a4 __attribute__((ext_vector_type(2), aligned(4)));
typedef float vfloat4_a4 __attribute__((ext_vector_type(4), aligned(4)));

__global__ __launch_bounds__(NTHREADS, 6) void warp_kernel(
    const float* __restrict__ image,   // [B,H,W,3]
    const float* __restrict__ flow,    // [B,H,W,2]
    float* __restrict__ out)           // [B,H,W,3]
{
    // +64 floats padding: clamped tail lanes of last staging issue land here
    __shared__ float win[WIN_ROWS * WSTRIDE + 64];   // 50176 B

    // ---- XCD-aware decomposition: blockIdx%8 = XCD = batch ----
    const int flat = blockIdx.x;            // 0..6143
    const int b    = flat & 7;
    const int s    = flat >> 3;             // 0..767 temporal order in XCD
    const int ty   = s / TILES_X;
    const int tx   = s - ty * TILES_X;
    const int Y0 = ty * TY, X0 = tx * TX;

    const int rowLo = min(max(Y0 - 16, 0), H - WIN_ROWS);
    const int colLo = min(max((X0 - 15) & ~3, 0), W - WIN_COLS);   // mult of 4

    const int lane = threadIdx.x & 63;
    const int wv   = threadIdx.x >> 6;      // 0..7

    // ---- async staging: issue all global_load_lds, no intervening waits ----
    const float* gwin = image + ((size_t)b * H + rowLo) * (W * C) + colLo * C;
#pragma unroll 1
    for (int j = wv; j * 64 < CHUNKS; j += 8) {
        int ci = j * 64 + lane;
        if (ci >= CHUNKS) ci = CHUNKS - 1;        // tail clamp -> LDS padding
        const int r = ci / 48;                    // magic-mul div
        const int c = ci - r * 48;
        const float* g = gwin + (size_t)r * (W * C) + c * 4;
        __builtin_amdgcn_global_load_lds(
            (const __attribute__((address_space(1))) void*)g,
            (__attribute__((address_space(3))) void*)(win + (size_t)j * 256),
            16, 0, 0);
    }

    // ---- flow loads before barrier: latency hides under staging ----
    vfloat2 f[PX_PER_T];
#pragma unroll
    for (int k = 0; k < PX_PER_T; ++k) {
        const int p   = threadIdx.x + k * NTHREADS;
        const int py  = p >> 5;
        const int pxx = p & 31;
        const size_t pix = ((size_t)b * H + (Y0 + py)) * W + (X0 + pxx);
        f[k] = __builtin_nontemporal_load((const vfloat2*)flow + pix);
    }

    __syncthreads();   // drains vmcnt: staging + flow complete

    // ---- compute: 2 px per thread, gathers served from LDS ----
#pragma unroll
    for (int k = 0; k < PX_PER_T; ++k) {
        const int p   = threadIdx.x + k * NTHREADS;
        const int py  = p >> 5;
        const int pxx = p & 31;
        const int y = Y0 + py;
        const int x = X0 + pxx;
        const size_t pix = ((size_t)b * H + y) * W + x;

        const float qy = (float)y - f[k].x;
        const float qx = (float)x - f[k].y;

        float y0f = floorf(qy);
        float x0f = floorf(qx);
        y0f = fminf(fmaxf(y0f, 0.0f), (float)(H - 2));
        x0f = fminf(fmaxf(x0f, 0.0f), (float)(W - 2));
        const float ay = fminf(fmaxf(qy - y0f, 0.0f), 1.0f);
        const float ax = fminf(fmaxf(qx - x0f, 0.0f), 1.0f);

        const int y0 = (int)y0f;
        const int x0 = (int)x0f;

        float tl0, tl1, tl2, tr0, tr1, tr2, bl0, bl1, bl2, br0, br1, br2;

        const bool inwin = (y0 >= rowLo) & (y0 <= rowLo + WIN_ROWS - 2) &
                           (x0 >= colLo) & (x0 <= colLo + WIN_COLS - 2);
        if (inwin) {
            const float* t = &win[(y0 - rowLo) * WSTRIDE + (x0 - colLo) * C];
            tl0 = t[0]; tl1 = t[1]; tl2 = t[2];
            tr0 = t[3]; tr1 = t[4]; tr2 = t[5];
            const float* bo = t + WSTRIDE;
            bl0 = bo[0]; bl1 = bo[1]; bl2 = bo[2];
            br0 = bo[3]; br1 = bo[4]; br2 = bo[5];
        } else {
            // rare (~0.4% px): flow beyond halo -> direct global bilinear
            const float* top = image + (((size_t)b * H + y0) * W + x0) * C;
            const float* bot = top + (size_t)W * C;
            const vfloat4 t4 = *(const vfloat4_a4*)top;
            const vfloat2 t2 = *(const vfloat2_a4*)(top + 4);
            const vfloat4 b4 = *(const vfloat4_a4*)bot;
            const vfloat2 b2 = *(const vfloat2_a4*)(bot + 4);
            tl0 = t4.x; tl1 = t4.y; tl2 = t4.z;
            tr0 = t4.w; tr1 = t2.x; tr2 = t2.y;
            bl0 = b4.x; bl1 = b4.y; bl2 = b4.z;
            br0 = b4.w; br1 = b2.x; br2 = b2.y;
        }

        const float tp0 = tl0 + ax * (tr0 - tl0);
        const float tp1 = tl1 + ax * (tr1 - tl1);
        const float tp2 = tl2 + ax * (tr2 - tl2);
        const float bo0 = bl0 + ax * (br0 - bl0);
        const float bo1 = bl1 + ax * (br1 - bl1);
        const float bo2 = bl2 + ax * (br2 - bl2);

        float* o = out + pix * C;
        __builtin_nontemporal_store(tp0 + ay * (bo0 - tp0), &o[0]);
        __builtin_nontemporal_store(tp1 + ay * (bo1 - tp1), &o[1]);
        __builtin_nontemporal_store(tp2 + ay * (bo2 - tp2), &o[2]);
    }
}

extern "C" void kernel_launch(void* const* d_in, const int* in_sizes, int n_in,
                              void* d_out, int out_size, void* d_ws, size_t ws_size,
                              hipStream_t stream) {
    const float* image = (const float*)d_in[0];
    const float* flow  = (const float*)d_in[1];
    float* out = (float*)d_out;

    dim3 grid(B * TILES_PER_B);   // 6144 blocks
    dim3 block(NTHREADS);
    warp_kernel<<<grid, block, 0, stream>>>(image, flow, out);
}